// Round 1
// baseline (4180.470 us; speedup 1.0000x reference)
//
#include <hip/hip_runtime.h>
#include <math.h>

#define BN_INV 0.99999500003749966f
#define NEG_BIG (-100000000.0f)

struct Params {
  const float* input;
  const void*  valid;
  const float *W1,*b1,*g1,*be1;
  const float *W2,*b2,*g2,*be2;
  const float *Wp1,*bp1;
  const float *W3,*b3,*g3,*be3;
  const float *Wp2,*bp2;
  const float *W4,*b4,*g4,*be4;
  const float *W5,*b5,*g5,*be5;
  const float *W6,*b6,*g6,*be6;
  const float *Wp4,*bp4;
  const float *W7,*b7,*g7,*be7;
  const float *W8,*b8,*g8,*be8;
  const float *Wp5,*bp5;
  const float *Wpi1,*bpi1,*Wpi2,*bpi2;
  const float *Wv1,*bv1,*Wv2,*bv2;
  float* out;
};

// Phase-1 matmul: rows = 8 elements * 7, N = 128 fixed.
// thread t: lane m=t&31 -> cols c0=4m; group e=t>>5 -> rows 7e..7e+6.
// epilogue: (acc + bias) * (g[j]*BN_INV) + be[j], relu.
template<int K>
__device__ __forceinline__ void mm_p1(const float* __restrict__ X,
                                      float* __restrict__ Y,
                                      const float* __restrict__ W,
                                      const float* __restrict__ bias,
                                      const float* __restrict__ g,
                                      const float* __restrict__ be)
{
  const int t = threadIdx.x;
  const int m = t & 31, e = t >> 5;
  const int c0 = m * 4;
  const float* Xr = X + e*7*128;
  float acc[7][4];
  #pragma unroll
  for (int j=0;j<7;j++){acc[j][0]=0.f;acc[j][1]=0.f;acc[j][2]=0.f;acc[j][3]=0.f;}
  for (int k=0;k<K;k+=4){
    float4 w[4];
    #pragma unroll
    for (int kk=0;kk<4;kk++) w[kk] = *(const float4*)(W + (k+kk)*128 + c0);
    #pragma unroll
    for (int j=0;j<7;j++){
      float4 xv = *(const float4*)(Xr + j*128 + k);
      float xx[4] = {xv.x, xv.y, xv.z, xv.w};
      #pragma unroll
      for (int kk=0;kk<4;kk++){
        acc[j][0] += xx[kk]*w[kk].x;
        acc[j][1] += xx[kk]*w[kk].y;
        acc[j][2] += xx[kk]*w[kk].z;
        acc[j][3] += xx[kk]*w[kk].w;
      }
    }
  }
  float4 bs = *(const float4*)(bias + c0);
  #pragma unroll
  for (int j=0;j<7;j++){
    float sc = g[j]*BN_INV;
    float bb = be[j];
    float4 o;
    o.x = fmaxf((acc[j][0]+bs.x)*sc + bb, 0.f);
    o.y = fmaxf((acc[j][1]+bs.y)*sc + bb, 0.f);
    o.z = fmaxf((acc[j][2]+bs.z)*sc + bb, 0.f);
    o.w = fmaxf((acc[j][3]+bs.w)*sc + bb, 0.f);
    *(float4*)(Y + (e*7+j)*128 + c0) = o;
  }
}

// Phase-1 dpg: group max/mean of cols 0..63 (8 groups of 8) -> out cols 0..15;
// dense: relu(x[64:128] @ Wp(64,112) + bp) -> out cols 16..127.
__device__ __forceinline__ void dpg_p1(const float* __restrict__ X,
                                       float* __restrict__ Y,
                                       const float* __restrict__ Wp,
                                       const float* __restrict__ bp)
{
  const int t = threadIdx.x;
  const int m = t & 31, e = t >> 5;
  const float* Xr = X + e*7*128;
  float* Yr = Y + e*7*128;
  if (m < 28) {
    const int c0 = m*4;
    float acc[7][4];
    #pragma unroll
    for (int j=0;j<7;j++){acc[j][0]=0.f;acc[j][1]=0.f;acc[j][2]=0.f;acc[j][3]=0.f;}
    for (int k=0;k<64;k+=4){
      float4 w[4];
      #pragma unroll
      for (int kk=0;kk<4;kk++) w[kk] = *(const float4*)(Wp + (k+kk)*112 + c0);
      #pragma unroll
      for (int j=0;j<7;j++){
        float4 xv = *(const float4*)(Xr + j*128 + 64 + k);
        float xx[4] = {xv.x, xv.y, xv.z, xv.w};
        #pragma unroll
        for (int kk=0;kk<4;kk++){
          acc[j][0] += xx[kk]*w[kk].x;
          acc[j][1] += xx[kk]*w[kk].y;
          acc[j][2] += xx[kk]*w[kk].z;
          acc[j][3] += xx[kk]*w[kk].w;
        }
      }
    }
    float4 bs = *(const float4*)(bp + c0);
    #pragma unroll
    for (int j=0;j<7;j++){
      float4 o;
      o.x = fmaxf(acc[j][0]+bs.x, 0.f);
      o.y = fmaxf(acc[j][1]+bs.y, 0.f);
      o.z = fmaxf(acc[j][2]+bs.z, 0.f);
      o.w = fmaxf(acc[j][3]+bs.w, 0.f);
      *(float4*)(Yr + j*128 + 16 + c0) = o;
    }
  } else if (m < 30) {
    #pragma unroll
    for (int j=0;j<7;j++){
      #pragma unroll
      for (int gi=0; gi<4; gi++){
        int gg = (m-28)*4 + gi;
        const float* p = Xr + j*128 + gg*8;
        float mx = p[0], sm = p[0];
        #pragma unroll
        for (int i=1;i<8;i++){ float v = p[i]; mx = fmaxf(mx, v); sm += v; }
        Yr[j*128 + gg] = mx;
        Yr[j*128 + 8 + gg] = sm*0.125f;
      }
    }
  }
}

// Flatten (B,7,128) tile -> (B,704): [max_{j<5} xb | mean_{j<5} xb | xb[5] | xb[6] | xe rows 0..6]
__device__ __forceinline__ void flatten_st(const float* __restrict__ X, float* __restrict__ F)
{
  const int t = threadIdx.x, m = t & 31, e = t >> 5;
  const float* Xr = X + e*7*128;
  float* Fr = F + e*704;
  for (int col=m; col<704; col+=32){
    float v;
    if (col < 64){
      float mx = Xr[col];
      #pragma unroll
      for (int j=1;j<5;j++) mx = fmaxf(mx, Xr[j*128+col]);
      v = mx;
    } else if (col < 128){
      int c = col-64;
      float sm = 0.f;
      #pragma unroll
      for (int j=0;j<5;j++) sm += Xr[j*128+c];
      v = sm*0.2f;
    } else if (col < 192){
      v = Xr[5*128 + (col-128)];
    } else if (col < 256){
      v = Xr[6*128 + (col-192)];
    } else {
      int q = col-256;
      v = Xr[(q>>6)*128 + 64 + (q&63)];
    }
    Fr[col] = v;
  }
}

// Phase-2 matmul: 8 rows. MODE 0: bias+bn+relu, 1: bias+relu, 2: bias only.
template<int K, int N, int RPG, int MODE>
__device__ __forceinline__ void mm_p2(const float* __restrict__ X, int sx,
                                      float* __restrict__ Y, int sy,
                                      const float* __restrict__ W,
                                      const float* __restrict__ bias,
                                      float sc, float bb)
{
  constexpr int NC4 = N/4;
  constexpr int NG  = (8 + RPG - 1) / RPG;
  const int t = threadIdx.x;
  const int ci = t % NC4;
  const int grp = t / NC4;
  if (grp < NG) {
    const int c0 = ci*4;
    const int r0 = grp*RPG;
    float acc[RPG][4];
    #pragma unroll
    for (int r=0;r<RPG;r++){acc[r][0]=0.f;acc[r][1]=0.f;acc[r][2]=0.f;acc[r][3]=0.f;}
    for (int k=0;k<K;k+=4){
      float4 w[4];
      #pragma unroll
      for (int kk=0;kk<4;kk++) w[kk] = *(const float4*)(W + (k+kk)*N + c0);
      #pragma unroll
      for (int r=0;r<RPG;r++){
        float4 xv = *(const float4*)(X + (r0+r)*sx + k);
        float xx[4] = {xv.x, xv.y, xv.z, xv.w};
        #pragma unroll
        for (int kk=0;kk<4;kk++){
          acc[r][0] += xx[kk]*w[kk].x;
          acc[r][1] += xx[kk]*w[kk].y;
          acc[r][2] += xx[kk]*w[kk].z;
          acc[r][3] += xx[kk]*w[kk].w;
        }
      }
    }
    float4 bs = *(const float4*)(bias + c0);
    #pragma unroll
    for (int r=0;r<RPG;r++){
      float o[4] = {acc[r][0]+bs.x, acc[r][1]+bs.y, acc[r][2]+bs.z, acc[r][3]+bs.w};
      #pragma unroll
      for (int q=0;q<4;q++){
        if (MODE == 0) o[q] = o[q]*sc + bb;
        if (MODE <= 1) o[q] = fmaxf(o[q], 0.f);
      }
      float4 ov = {o[0],o[1],o[2],o[3]};
      *(float4*)(Y + (r0+r)*sy + c0) = ov;
    }
  }
}

// Phase-2 dpg group part: max/mean of cols 0..63 (8 groups) -> out cols 0..15. Strides fixed 256.
__device__ __forceinline__ void dpg_p2_group(const float* __restrict__ X,
                                             float* __restrict__ Y)
{
  const int t = threadIdx.x;
  if (t < 128){
    int r = t >> 4, g0 = t & 15;
    const float* p = X + r*256 + (g0&7)*8;
    float mx = p[0], sm = p[0];
    #pragma unroll
    for (int i=1;i<8;i++){ float v = p[i]; mx = fmaxf(mx, v); sm += v; }
    Y[r*256 + g0] = (g0 < 8) ? mx : sm*0.125f;
  }
}

__global__ __launch_bounds__(256, 2)
void splendor_fwd(Params P, int Bt)
{
  __shared__ float bufA[7168];
  __shared__ float bufB[7168];
  __shared__ int sflags[2];
  const int t = threadIdx.x;
  const int b0 = blockIdx.x * 8;

  if (t < 2) sflags[t] = 0;
  __syncthreads();

  // --- detect valid_actions storage dtype (uint8 bool / int32 / float32) ---
  {
    const unsigned int* vw = (const unsigned int*)P.valid;
    int f3 = 0, nz = 0;
    #pragma unroll
    for (int i=0;i<4;i++){
      unsigned int u = vw[t*4 + i];
      if (u & 0xFFFFFF00u) nz = 1;
      if (((u>>24)&0xFFu)==0x3Fu || ((u>>16)&0xFFu)==0x3Fu ||
          ((u>>8)&0xFFu)==0x3Fu  || (u&0xFFu)==0x3Fu) f3 = 1;
    }
    if (f3) atomicOr(&sflags[0], 1);
    if (nz) atomicOr(&sflags[1], 1);
  }
  // --- load + transpose input: (8,56,7) -> LDS rows (e*7+j), cols i ---
  {
    const float* inp = P.input + (size_t)b0*392;
    for (int f=t; f<3136; f+=256){
      int e = f/392, rem = f - e*392;
      int i = rem/7, j = rem - i*7;
      bufA[(e*7+j)*128 + i] = inp[f];
    }
  }
  __syncthreads();
  const int vmode = sflags[0] ? 2 : (sflags[1] ? 0 : 1); // 2=float32, 0=uint8, 1=int32

  // -------- phase 1: rows = 56 (8 elems x 7) --------
  mm_p1<56>(bufA, bufB, P.W1, P.b1, P.g1, P.be1);   __syncthreads();
  mm_p1<128>(bufB, bufA, P.W2, P.b2, P.g2, P.be2);  __syncthreads();
  dpg_p1(bufA, bufB, P.Wp1, P.bp1);                 __syncthreads();
  mm_p1<128>(bufB, bufA, P.W3, P.b3, P.g3, P.be3);  __syncthreads();
  dpg_p1(bufA, bufB, P.Wp2, P.bp2);                 __syncthreads();
  mm_p1<128>(bufB, bufA, P.W4, P.b4, P.g4, P.be4);  __syncthreads();
  flatten_st(bufA, bufB);                           __syncthreads();

  // -------- phase 2: rows = 8 --------
  mm_p2<704,512,4,0>(bufB,704, bufA,512, P.W5, P.b5, P.g5[0]*BN_INV, P.be5[0]); __syncthreads();
  mm_p2<512,256,2,0>(bufA,512, bufB,256, P.W6, P.b6, P.g6[0]*BN_INV, P.be6[0]); __syncthreads();
  mm_p2<192,240,2,1>(bufB+64,256, bufA+16,256, P.Wp4, P.bp4, 0.f, 0.f);
  dpg_p2_group(bufB, bufA);                         __syncthreads();
  mm_p2<256,256,2,0>(bufA,256, bufB,256, P.W7, P.b7, P.g7[0]*BN_INV, P.be7[0]); __syncthreads();
  mm_p2<256,256,2,0>(bufB,256, bufA,256, P.W8, P.b8, P.g8[0]*BN_INV, P.be8[0]); __syncthreads();
  mm_p2<192,240,2,1>(bufA+64,256, bufB+16,256, P.Wp5, P.bp5, 0.f, 0.f);
  dpg_p2_group(bufA, bufB);                         __syncthreads();
  // heads' hidden layers (bias only, no activation)
  mm_p2<256,256,2,2>(bufB,256, bufA,256,      P.Wpi1, P.bpi1, 0.f, 0.f);
  mm_p2<256,256,2,2>(bufB,256, bufA+2048,256, P.Wv1,  P.bv1,  0.f, 0.f);
  __syncthreads();

  // -------- pi logits + mask + log_softmax --------
  {
    const int r = t >> 5, l = t & 31;
    const int b = b0 + r;
    const float* hp = bufA + r*256;
    float pm[3] = {NEG_BIG, NEG_BIG, NEG_BIG};
    float mx = -INFINITY;
    #pragma unroll
    for (int p=0;p<3;p++){
      int c = l + 32*p;
      if (c < 81){
        float s = P.bpi2[c];
        for (int k=0;k<256;k++) s += hp[k]*P.Wpi2[k*81+c];
        bool valid;
        size_t idx = (size_t)b*81 + c;
        if (vmode == 0)      valid = ((const unsigned char*)P.valid)[idx] != 0;
        else if (vmode == 1) valid = ((const int*)P.valid)[idx] != 0;
        else                 valid = ((const float*)P.valid)[idx] != 0.f;
        pm[p] = valid ? s : NEG_BIG;
        mx = fmaxf(mx, pm[p]);
      }
    }
    #pragma unroll
    for (int off=16;off;off>>=1) mx = fmaxf(mx, __shfl_xor(mx, off, 32));
    float se = 0.f;
    #pragma unroll
    for (int p=0;p<3;p++){
      int c = l + 32*p;
      if (c < 81) se += expf(pm[p]-mx);
    }
    #pragma unroll
    for (int off=16;off;off>>=1) se += __shfl_xor(se, off, 32);
    float lse = mx + logf(se);
    #pragma unroll
    for (int p=0;p<3;p++){
      int c = l + 32*p;
      if (c < 81) P.out[(size_t)b*81 + c] = pm[p]-lse;
    }
  }

  // -------- value head --------
  if (t < 8){
    const float* hv = bufA + 2048 + t*256;
    float s = P.bv2[0];
    for (int k=0;k<256;k++) s += hv[k]*P.Wv2[k];
    P.out[(size_t)Bt*81 + b0 + t] = tanhf(s);
  }
}

extern "C" void kernel_launch(void* const* d_in, const int* in_sizes, int n_in,
                              void* d_out, int out_size, void* d_ws, size_t ws_size,
                              hipStream_t stream)
{
  Params P;
  P.input = (const float*)d_in[0];
  P.valid = d_in[1];
  P.W1  = (const float*)d_in[2];  P.b1  = (const float*)d_in[3];
  P.g1  = (const float*)d_in[4];  P.be1 = (const float*)d_in[5];
  P.W2  = (const float*)d_in[6];  P.b2  = (const float*)d_in[7];
  P.g2  = (const float*)d_in[8];  P.be2 = (const float*)d_in[9];
  P.Wp1 = (const float*)d_in[10]; P.bp1 = (const float*)d_in[11];
  P.W3  = (const float*)d_in[12]; P.b3  = (const float*)d_in[13];
  P.g3  = (const float*)d_in[14]; P.be3 = (const float*)d_in[15];
  P.Wp2 = (const float*)d_in[16]; P.bp2 = (const float*)d_in[17];
  P.W4  = (const float*)d_in[18]; P.b4  = (const float*)d_in[19];
  P.g4  = (const float*)d_in[20]; P.be4 = (const float*)d_in[21];
  P.W5  = (const float*)d_in[22]; P.b5  = (const float*)d_in[23];
  P.g5  = (const float*)d_in[24]; P.be5 = (const float*)d_in[25];
  P.W6  = (const float*)d_in[26]; P.b6  = (const float*)d_in[27];
  P.g6  = (const float*)d_in[28]; P.be6 = (const float*)d_in[29];
  P.Wp4 = (const float*)d_in[30]; P.bp4 = (const float*)d_in[31];
  P.W7  = (const float*)d_in[32]; P.b7  = (const float*)d_in[33];
  P.g7  = (const float*)d_in[34]; P.be7 = (const float*)d_in[35];
  P.W8  = (const float*)d_in[36]; P.b8  = (const float*)d_in[37];
  P.g8  = (const float*)d_in[38]; P.be8 = (const float*)d_in[39];
  P.Wp5 = (const float*)d_in[40]; P.bp5 = (const float*)d_in[41];
  P.Wpi1= (const float*)d_in[42]; P.bpi1= (const float*)d_in[43];
  P.Wpi2= (const float*)d_in[44]; P.bpi2= (const float*)d_in[45];
  P.Wv1 = (const float*)d_in[46]; P.bv1 = (const float*)d_in[47];
  P.Wv2 = (const float*)d_in[48]; P.bv2 = (const float*)d_in[49];
  P.out = (float*)d_out;

  int Bt = in_sizes[0] / 392;           // 65536
  dim3 grid(Bt/8), block(256);
  hipLaunchKernelGGL(splendor_fwd, grid, block, 0, stream, P, Bt);
}

// Round 3
// 740.636 us; speedup vs baseline: 5.6444x; 5.6444x over previous
//
#include <hip/hip_runtime.h>
#include <hip/hip_bf16.h>
#include <math.h>

#define BN_INV 0.99999500003749966f
#define NEG_BIG (-100000000.0f)

typedef __attribute__((ext_vector_type(8))) short s16x8;
typedef __attribute__((ext_vector_type(4))) float f32x4;

#define MFMA16(a,b,c) __builtin_amdgcn_mfma_f32_16x16x32_bf16(a,b,c,0,0,0)

__device__ __forceinline__ ushort f2b(float f){
  unsigned u = __builtin_bit_cast(unsigned, f);
  unsigned r = (u + 0x7FFFu + ((u>>16)&1u)) >> 16;
  return (ushort)r;
}
__device__ __forceinline__ float b2f(ushort h){
  unsigned u = ((unsigned)h)<<16; return __builtin_bit_cast(float, u);
}

// ---------------- packed-weight offsets in ws (halfword units) ----------------
// layout: bf16, [(K/8)][N][8] per weight
#define OFF_W1   0
#define OFF_W2   8192
#define OFF_W3   24576
#define OFF_W4   40960
#define OFF_WP1  57344
#define OFF_WP2  64512
#define OFF_W5   71680
#define OFF_W6   432128
#define OFF_WP4  563200
#define OFF_WP5  609280
#define OFF_W7   655360
#define OFF_W8   720896
#define OFF_WPI1 786432
#define OFF_WPI2 851968
#define OFF_WV1  876544
#define OFF_X    942080

// ============================ prep: fp32 -> packed bf16 ============================
struct PrepParams {
  const float* src[15];
  long long off[15];
  int K[15], N[15], Kp[15], Np[15];
  ushort* ws;
};

__global__ void prep_pack(PrepParams pp){
  int wi = blockIdx.y;
  const float* s = pp.src[wi];
  ushort* d = pp.ws + pp.off[wi];
  int K = pp.K[wi], N = pp.N[wi], Np = pp.Np[wi];
  int tot = pp.Kp[wi]*Np;
  for (int idx = blockIdx.x*blockDim.x + threadIdx.x; idx < tot; idx += gridDim.x*blockDim.x){
    int k = idx / Np, j = idx - k*Np;
    float v = (k < K && j < N) ? s[k*N + j] : 0.f;
    d[(((k>>3)*Np + j)<<3) + (k&7)] = f2b(v);
  }
}

// ============================ phase-1 kernel ============================
// 16 batch elements/block, 256 threads (4 waves). LDS rows = 112 (e*7+j),
// bf16, row stride 136 halfwords (16B-aligned, bank stride 4 -> 2-way free).
#define S1 136

struct P1 {
  const float* inp; const ushort* ws; ushort* xout;
  const float *b1,*g1,*be1,*b2,*g2,*be2,*bp1,*b3,*g3,*be3,*bp2,*b4,*g4,*be4;
};

// N=128 layer: 8 n-tiles over 4 waves (2 each), 7 m-tiles, bn(g[j],be[j])+relu.
template<int KT>
__device__ __forceinline__ void p1_mm(const ushort* X, ushort* Y, const ushort* W,
    const float* bias, const float* g, const float* be, int t){
  const int l=t&63, w=t>>6, lo=l&15, hi=l>>4;
  s16x8 Bf[2][KT];
  #pragma unroll
  for (int nt=0;nt<2;nt++)
    #pragma unroll
    for (int kt=0;kt<KT;kt++)
      Bf[nt][kt] = *(const s16x8*)(W + (((kt*4+hi)*128 + (w*2+nt)*16 + lo)<<3));
  float bc0 = bias[(w*2)*16+lo], bc1 = bias[(w*2+1)*16+lo];
  for (int mt=0; mt<7; mt++){
    const int rowb = mt*16;
    s16x8 Af[KT];
    #pragma unroll
    for (int kt=0;kt<KT;kt++)
      Af[kt] = *(const s16x8*)(X + (rowb+lo)*S1 + kt*32 + hi*8);
    f32x4 a0 = {0.f,0.f,0.f,0.f}, a1 = {0.f,0.f,0.f,0.f};
    #pragma unroll
    for (int kt=0;kt<KT;kt++){
      a0 = MFMA16(Af[kt], Bf[0][kt], a0);
      a1 = MFMA16(Af[kt], Bf[1][kt], a1);
    }
    #pragma unroll
    for (int r=0;r<4;r++){
      int row = rowb + hi*4 + r;
      int j = row % 7;
      float scj = g[j]*BN_INV, bbj = be[j];
      float v0 = fmaxf((a0[r]+bc0)*scj + bbj, 0.f);
      float v1 = fmaxf((a1[r]+bc1)*scj + bbj, 0.f);
      Y[row*S1 + (w*2)*16 + lo]   = f2b(v0);
      Y[row*S1 + (w*2+1)*16 + lo] = f2b(v1);
    }
  }
}

// dpg: group max/mean (cols0..63 -> out 0..15) + relu(X[:,64:128]@Wp+bp) -> out 16..127
__device__ __forceinline__ void p1_dpg(const ushort* X, ushort* Y, const ushort* Wp,
                                       const float* bp, int t){
  const int l=t&63, w=t>>6, lo=l&15, hi=l>>4;
  const int nt0 = 2*w;
  const int ntn = (w<3) ? 2 : 1;   // 7 n-tiles over 4 waves
  s16x8 Bf[2][2];
  #pragma unroll
  for (int nt=0;nt<2;nt++)
    if (nt < ntn)
      #pragma unroll
      for (int kt=0;kt<2;kt++)
        Bf[nt][kt] = *(const s16x8*)(Wp + (((kt*4+hi)*112 + (nt0+nt)*16 + lo)<<3));
  float bc[2];
  #pragma unroll
  for (int nt=0;nt<2;nt++) bc[nt] = (nt<ntn) ? bp[(nt0+nt)*16+lo] : 0.f;
  for (int mt=0; mt<7; mt++){
    const int rowb = mt*16;
    s16x8 Af[2];
    #pragma unroll
    for (int kt=0;kt<2;kt++)
      Af[kt] = *(const s16x8*)(X + (rowb+lo)*S1 + 64 + kt*32 + hi*8);
    f32x4 acc0 = {0.f,0.f,0.f,0.f}, acc1 = {0.f,0.f,0.f,0.f};
    #pragma unroll
    for (int kt=0;kt<2;kt++){
      acc0 = MFMA16(Af[kt], Bf[0][kt], acc0);
      if (ntn > 1) acc1 = MFMA16(Af[kt], Bf[1][kt], acc1);
    }
    #pragma unroll
    for (int r=0;r<4;r++){
      int row = rowb + hi*4 + r;
      Y[row*S1 + 16 + nt0*16 + lo] = f2b(fmaxf(acc0[r] + bc[0], 0.f));
      if (ntn > 1)
        Y[row*S1 + 16 + (nt0+1)*16 + lo] = f2b(fmaxf(acc1[r] + bc[1], 0.f));
    }
  }
  if (w == 3){
    #pragma unroll
    for (int i=0;i<14;i++){     // 112 rows * 8 groups = 896 tasks / 64 lanes
      int tau = l + 64*i;
      int row = tau>>3, gg = tau&7;
      s16x8 v8 = *(const s16x8*)(X + row*S1 + gg*8);
      float mx = b2f((ushort)v8[0]), smv = mx;
      #pragma unroll
      for (int q2=1;q2<8;q2++){ float vv = b2f((ushort)v8[q2]); mx = fmaxf(mx,vv); smv += vv; }
      Y[row*S1 + gg]     = f2b(mx);
      Y[row*S1 + 8 + gg] = f2b(smv*0.125f);
    }
  }
}

__global__ __launch_bounds__(256,2) void p1_kernel(P1 P){
  __shared__ ushort sA[112*S1];
  __shared__ ushort sB[112*S1];
  const int t = threadIdx.x;
  const size_t b0 = (size_t)blockIdx.x*16;
  const float* ip = P.inp + b0*392;
  for (int f=t; f<16*392; f+=256){
    int e = f/392, rem = f - e*392;
    int i = rem/7, j = rem - i*7;
    sA[(e*7+j)*S1 + i] = f2b(ip[f]);
  }
  for (int idx=t; idx<112*8; idx+=256)      // zero k-pad cols 56..63 (W1 K padded)
    sA[(idx>>3)*S1 + 56 + (idx&7)] = 0;
  __syncthreads();
  p1_mm<2>(sA,sB, P.ws+OFF_W1, P.b1,P.g1,P.be1, t); __syncthreads();
  p1_mm<4>(sB,sA, P.ws+OFF_W2, P.b2,P.g2,P.be2, t); __syncthreads();
  p1_dpg(sA,sB, P.ws+OFF_WP1, P.bp1, t);            __syncthreads();
  p1_mm<4>(sB,sA, P.ws+OFF_W3, P.b3,P.g3,P.be3, t); __syncthreads();
  p1_dpg(sA,sB, P.ws+OFF_WP2, P.bp2, t);            __syncthreads();
  p1_mm<4>(sB,sA, P.ws+OFF_W4, P.b4,P.g4,P.be4, t); __syncthreads();
  // flatten -> x704 bf16 in ws
  ushort* xo = P.xout + b0*704;
  for (int idx=t; idx<16*704; idx+=256){
    int e = idx/704, c = idx - e*704;
    const ushort* Xr = sA + e*7*S1;
    float v;
    if (c < 64){
      float mx = b2f(Xr[c]);
      #pragma unroll
      for (int j=1;j<5;j++) mx = fmaxf(mx, b2f(Xr[j*S1+c]));
      v = mx;
    } else if (c < 128){
      int cc = c-64; float smv = 0.f;
      #pragma unroll
      for (int j=0;j<5;j++) smv += b2f(Xr[j*S1+cc]);
      v = smv*0.2f;
    } else if (c < 192) v = b2f(Xr[5*S1 + c-128]);
    else if (c < 256)   v = b2f(Xr[6*S1 + c-192]);
    else { int q2 = c-256; v = b2f(Xr[(q2>>6)*S1 + 64 + (q2&63)]); }
    xo[idx] = f2b(v);
  }
}

// ============================ phase-2 kernel ============================
// 64 rows/block, 512 threads (8 waves). LDS union:
//  A0: x704  (stride 712 hw) bytes [0, 91136)
//  A1: y512  (stride 520 hw) bytes [91136, 157696)
//  B0/B1: 256-wide (stride 264 hw) at bytes 0 / 33792 (inside dead A0)
//  C: 256-wide at byte 91136 (inside dead A1)
//  Lf: f32 logits (stride 104 f32) over B0 region
#define SX 712
#define SY 520
#define SZ 264

struct P2 {
  const ushort* x; const ushort* ws; const void* valid;
  const float *b5,*g5,*be5,*b6,*g6,*be6,*bp4,*b7,*g7,*be7,*b8,*g8,*be8,*bp5;
  const float *bpi1,*bpi2,*bv1,*Wv2,*bv2;
  float* out; long long Btot;
};

// wave covers all 4 m-tiles x NTW n-tiles at n0. MODE: 0 bn+relu, 1 relu, 2 none, 3 none+f32 store
template<int KT, int NTW, int WN, int MODE>
__device__ __forceinline__ void p2_mm(const ushort* X, int sx, int xoff,
    ushort* Y, int sy, int yoff, const ushort* W, int n0,
    const float* bias, int bmax, float sc, float bb, int lo, int hi, int nact)
{
  f32x4 acc[4][NTW];
  #pragma unroll
  for (int m=0;m<4;m++)
    #pragma unroll
    for (int n=0;n<NTW;n++)
      acc[m][n] = (f32x4){0.f,0.f,0.f,0.f};
  for (int kt=0; kt<KT; kt++){
    s16x8 Af[4];
    #pragma unroll
    for (int m=0;m<4;m++)
      Af[m] = *(const s16x8*)(X + (m*16+lo)*sx + xoff + kt*32 + hi*8);
    s16x8 Bf[NTW];
    #pragma unroll
    for (int n=0;n<NTW;n++)
      if (n < nact)
        Bf[n] = *(const s16x8*)(W + (((size_t)(kt*4+hi)*WN + n0 + n*16 + lo)<<3));
    #pragma unroll
    for (int m=0;m<4;m++)
      #pragma unroll
      for (int n=0;n<NTW;n++)
        if (n < nact)
          acc[m][n] = MFMA16(Af[m], Bf[n], acc[m][n]);
  }
  #pragma unroll
  for (int n=0;n<NTW;n++){
    if (n < nact){
      int colw = n0 + n*16 + lo;
      float bc = (colw < bmax) ? bias[colw] : 0.f;
      #pragma unroll
      for (int m=0;m<4;m++){
        #pragma unroll
        for (int r=0;r<4;r++){
          int row = m*16 + hi*4 + r;
          float v = acc[m][n][r] + bc;
          if (MODE==0) v = fmaxf(v*sc+bb, 0.f);
          else if (MODE==1) v = fmaxf(v, 0.f);
          if (MODE==3) ((float*)Y)[row*sy + yoff + colw] = v;
          else Y[row*sy + yoff + colw] = f2b(v);
        }
      }
    }
  }
}

__device__ __forceinline__ void p2_group(const ushort* X, ushort* Y, int t){
  int row = t>>3, gg = t&7;   // 512 threads = 64 rows x 8 groups
  s16x8 v8 = *(const s16x8*)(X + row*SZ + gg*8);
  float mx = b2f((ushort)v8[0]), smv = mx;
  #pragma unroll
  for (int q2=1;q2<8;q2++){ float vv = b2f((ushort)v8[q2]); mx = fmaxf(mx,vv); smv += vv; }
  Y[row*SZ + gg]     = f2b(mx);
  Y[row*SZ + 8 + gg] = f2b(smv*0.125f);
}

__global__ __launch_bounds__(512,2) void p2_kernel(P2 P){
  __shared__ ushort sm[78848];
  __shared__ int sflags[2];
  ushort* A0 = sm;
  ushort* A1 = sm + 45568;
  ushort* B0 = sm;
  ushort* B1 = sm + 16896;
  ushort* C  = sm + 45568;
  float*  Lf = (float*)sm;
  const int t = threadIdx.x;
  const int l = t&63, w = t>>6, lo = l&15, hi = l>>4;
  const size_t b0 = (size_t)blockIdx.x * 64;

  if (t < 2) sflags[t] = 0;
  __syncthreads();
  if (t < 256){
    const unsigned* vw = (const unsigned*)P.valid;
    int f3=0, nz=0;
    #pragma unroll
    for (int i=0;i<4;i++){
      unsigned u = vw[t*4+i];
      if (u & 0xFFFFFF00u) nz=1;
      if (((u>>24)&0xFFu)==0x3Fu || ((u>>16)&0xFFu)==0x3Fu ||
          ((u>>8)&0xFFu)==0x3Fu  || (u&0xFFu)==0x3Fu) f3=1;
    }
    if (f3) atomicOr(&sflags[0],1);
    if (nz) atomicOr(&sflags[1],1);
  }
  const ushort* xi = P.x + b0*704;
  for (int ci = t; ci < 64*88; ci += 512){
    int row = ci/88, c8 = ci - row*88;
    *(s16x8*)(A0 + row*SX + c8*8) = *(const s16x8*)(xi + row*704 + c8*8);
  }
  __syncthreads();
  const int vmode = sflags[0] ? 2 : (sflags[1] ? 0 : 1);
  float sc, bb;
  sc = P.g5[0]*BN_INV; bb = P.be5[0];
  p2_mm<22,4,512,0>(A0,SX,0, A1,SY,0, P.ws+OFF_W5, w*64, P.b5,512, sc,bb, lo,hi, 4);
  __syncthreads();
  sc = P.g6[0]*BN_INV; bb = P.be6[0];
  p2_mm<16,2,256,0>(A1,SY,0, B0,SZ,0, P.ws+OFF_W6, w*32, P.b6,256, sc,bb, lo,hi, 2);
  __syncthreads();
  p2_group(B0, B1, t);
  p2_mm<6,2,240,1>(B0,SZ,64, B1,SZ,16, P.ws+OFF_WP4, w*32, P.bp4,240, 0.f,0.f, lo,hi, (w==7)?1:2);
  __syncthreads();
  sc = P.g7[0]*BN_INV; bb = P.be7[0];
  p2_mm<8,2,256,0>(B1,SZ,0, B0,SZ,0, P.ws+OFF_W7, w*32, P.b7,256, sc,bb, lo,hi, 2);
  __syncthreads();
  sc = P.g8[0]*BN_INV; bb = P.be8[0];
  p2_mm<8,2,256,0>(B0,SZ,0, B1,SZ,0, P.ws+OFF_W8, w*32, P.b8,256, sc,bb, lo,hi, 2);
  __syncthreads();
  p2_group(B1, B0, t);
  p2_mm<6,2,240,1>(B1,SZ,64, B0,SZ,16, P.ws+OFF_WP5, w*32, P.bp5,240, 0.f,0.f, lo,hi, (w==7)?1:2);
  __syncthreads();
  p2_mm<8,2,256,2>(B0,SZ,0, B1,SZ,0, P.ws+OFF_WPI1, w*32, P.bpi1,256, 0.f,0.f, lo,hi, 2);
  p2_mm<8,2,256,2>(B0,SZ,0, C ,SZ,0, P.ws+OFF_WV1,  w*32, P.bv1, 256, 0.f,0.f, lo,hi, 2);
  __syncthreads();
  if (w < 6){
    p2_mm<8,1,96,3>(B1,SZ,0, (ushort*)Lf,104,0, P.ws+OFF_WPI2, w*16, P.bpi2,81, 0.f,0.f, lo,hi, 1);
  } else {
    int idx = (w-6)*64 + l;      // 128 threads, 2 per row
    int row = idx>>1, half = idx&1;
    const ushort* hv = C + row*SZ + half*128;
    float s = 0.f;
    for (int k=0;k<128;k++) s += b2f(hv[k]) * P.Wv2[half*128+k];
    s += __shfl_xor(s, 1);
    if (!half) P.out[(size_t)P.Btot*81 + b0 + row] = tanhf(s + P.bv2[0]);
  }
  __syncthreads();
  {
    int row = t>>3, q = t&7;
    size_t b = b0 + row;
    const float* lr = Lf + row*104;
    float pm[11]; float mx = -INFINITY;
    #pragma unroll
    for (int i=0;i<11;i++){
      int c = q + 8*i;
      float v = NEG_BIG;
      if (c < 81){
        float sv = lr[c];
        bool valid;
        size_t vidx = b*81 + c;
        if (vmode==0)      valid = ((const unsigned char*)P.valid)[vidx] != 0;
        else if (vmode==1) valid = ((const int*)P.valid)[vidx] != 0;
        else               valid = ((const float*)P.valid)[vidx] != 0.f;
        v = valid ? sv : NEG_BIG;
      }
      pm[i] = v;
      mx = fmaxf(mx, v);
    }
    #pragma unroll
    for (int o=4;o;o>>=1) mx = fmaxf(mx, __shfl_xor(mx, o));
    float se = 0.f;
    #pragma unroll
    for (int i=0;i<11;i++){
      int c = q + 8*i;
      if (c < 81) se += expf(pm[i]-mx);
    }
    #pragma unroll
    for (int o=4;o;o>>=1) se += __shfl_xor(se, o);
    float lse = mx + logf(se);
    #pragma unroll
    for (int i=0;i<11;i++){
      int c = q + 8*i;
      if (c < 81) P.out[b*81 + c] = pm[i] - lse;
    }
  }
}

// ============================ fp32 fallback (proven, R1) ============================
struct Params {
  const float* input;
  const void*  valid;
  const float *W1,*b1,*g1,*be1, *W2,*b2,*g2,*be2, *Wp1,*bp1;
  const float *W3,*b3,*g3,*be3, *Wp2,*bp2, *W4,*b4,*g4,*be4;
  const float *W5,*b5,*g5,*be5, *W6,*b6,*g6,*be6, *Wp4,*bp4;
  const float *W7,*b7,*g7,*be7, *W8,*b8,*g8,*be8, *Wp5,*bp5;
  const float *Wpi1,*bpi1,*Wpi2,*bpi2, *Wv1,*bv1,*Wv2,*bv2;
  float* out;
};

template<int K>
__device__ __forceinline__ void mm_p1(const float* __restrict__ X, float* __restrict__ Y,
    const float* __restrict__ W, const float* __restrict__ bias,
    const float* __restrict__ g, const float* __restrict__ be){
  const int t = threadIdx.x;
  const int m = t & 31, e = t >> 5;
  const int c0 = m * 4;
  const float* Xr = X + e*7*128;
  float acc[7][4];
  #pragma unroll
  for (int j=0;j<7;j++){acc[j][0]=0.f;acc[j][1]=0.f;acc[j][2]=0.f;acc[j][3]=0.f;}
  for (int k=0;k<K;k+=4){
    float4 wv[4];
    #pragma unroll
    for (int kk=0;kk<4;kk++) wv[kk] = *(const float4*)(W + (k+kk)*128 + c0);
    #pragma unroll
    for (int j=0;j<7;j++){
      float4 xv = *(const float4*)(Xr + j*128 + k);
      float xx[4] = {xv.x, xv.y, xv.z, xv.w};
      #pragma unroll
      for (int kk=0;kk<4;kk++){
        acc[j][0] += xx[kk]*wv[kk].x; acc[j][1] += xx[kk]*wv[kk].y;
        acc[j][2] += xx[kk]*wv[kk].z; acc[j][3] += xx[kk]*wv[kk].w;
      }
    }
  }
  float4 bs = *(const float4*)(bias + c0);
  #pragma unroll
  for (int j=0;j<7;j++){
    float sc = g[j]*BN_INV; float bb = be[j];
    float4 o;
    o.x = fmaxf((acc[j][0]+bs.x)*sc + bb, 0.f);
    o.y = fmaxf((acc[j][1]+bs.y)*sc + bb, 0.f);
    o.z = fmaxf((acc[j][2]+bs.z)*sc + bb, 0.f);
    o.w = fmaxf((acc[j][3]+bs.w)*sc + bb, 0.f);
    *(float4*)(Y + (e*7+j)*128 + c0) = o;
  }
}

__device__ __forceinline__ void dpg_p1f(const float* __restrict__ X, float* __restrict__ Y,
    const float* __restrict__ Wp, const float* __restrict__ bp){
  const int t = threadIdx.x;
  const int m = t & 31, e = t >> 5;
  const float* Xr = X + e*7*128;
  float* Yr = Y + e*7*128;
  if (m < 28) {
    const int c0 = m*4;
    float acc[7][4];
    #pragma unroll
    for (int j=0;j<7;j++){acc[j][0]=0.f;acc[j][1]=0.f;acc[j][2]=0.f;acc[j][3]=0.f;}
    for (int k=0;k<64;k+=4){
      float4 wv[4];
      #pragma unroll
      for (int kk=0;kk<4;kk++) wv[kk] = *(const float4*)(Wp + (k+kk)*112 + c0);
      #pragma unroll
      for (int j=0;j<7;j++){
        float4 xv = *(const float4*)(Xr + j*128 + 64 + k);
        float xx[4] = {xv.x, xv.y, xv.z, xv.w};
        #pragma unroll
        for (int kk=0;kk<4;kk++){
          acc[j][0] += xx[kk]*wv[kk].x; acc[j][1] += xx[kk]*wv[kk].y;
          acc[j][2] += xx[kk]*wv[kk].z; acc[j][3] += xx[kk]*wv[kk].w;
        }
      }
    }
    float4 bs = *(const float4*)(bp + c0);
    #pragma unroll
    for (int j=0;j<7;j++){
      float4 o;
      o.x = fmaxf(acc[j][0]+bs.x, 0.f); o.y = fmaxf(acc[j][1]+bs.y, 0.f);
      o.z = fmaxf(acc[j][2]+bs.z, 0.f); o.w = fmaxf(acc[j][3]+bs.w, 0.f);
      *(float4*)(Yr + j*128 + 16 + c0) = o;
    }
  } else if (m < 30) {
    #pragma unroll
    for (int j=0;j<7;j++){
      #pragma unroll
      for (int gi=0; gi<4; gi++){
        int gg = (m-28)*4 + gi;
        const float* p = Xr + j*128 + gg*8;
        float mx = p[0], smv = p[0];
        #pragma unroll
        for (int i=1;i<8;i++){ float v = p[i]; mx = fmaxf(mx, v); smv += v; }
        Yr[j*128 + gg] = mx;
        Yr[j*128 + 8 + gg] = smv*0.125f;
      }
    }
  }
}

__device__ __forceinline__ void flatten_st(const float* __restrict__ X, float* __restrict__ F){
  const int t = threadIdx.x, m = t & 31, e = t >> 5;
  const float* Xr = X + e*7*128;
  float* Fr = F + e*704;
  for (int col=m; col<704; col+=32){
    float v;
    if (col < 64){
      float mx = Xr[col];
      #pragma unroll
      for (int j=1;j<5;j++) mx = fmaxf(mx, Xr[j*128+col]);
      v = mx;
    } else if (col < 128){
      int c = col-64; float smv = 0.f;
      #pragma unroll
      for (int j=0;j<5;j++) smv += Xr[j*128+c];
      v = smv*0.2f;
    } else if (col < 192){ v = Xr[5*128 + (col-128)];
    } else if (col < 256){ v = Xr[6*128 + (col-192)];
    } else { int q = col-256; v = Xr[(q>>6)*128 + 64 + (q&63)]; }
    Fr[col] = v;
  }
}

template<int K, int N, int RPG, int MODE>
__device__ __forceinline__ void mm_p2(const float* __restrict__ X, int sx,
    float* __restrict__ Y, int sy, const float* __restrict__ W,
    const float* __restrict__ bias, float sc, float bb){
  constexpr int NC4 = N/4;
  constexpr int NG  = (8 + RPG - 1) / RPG;
  const int t = threadIdx.x;
  const int ci = t % NC4;
  const int grp = t / NC4;
  if (grp < NG) {
    const int c0 = ci*4;
    const int r0 = grp*RPG;
    float acc[RPG][4];
    #pragma unroll
    for (int r=0;r<RPG;r++){acc[r][0]=0.f;acc[r][1]=0.f;acc[r][2]=0.f;acc[r][3]=0.f;}
    for (int k=0;k<K;k+=4){
      float4 wv[4];
      #pragma unroll
      for (int kk=0;kk<4;kk++) wv[kk] = *(const float4*)(W + (k+kk)*N + c0);
      #pragma unroll
      for (int r=0;r<RPG;r++){
        float4 xv = *(const float4*)(X + (r0+r)*sx + k);
        float xx[4] = {xv.x, xv.y, xv.z, xv.w};
        #pragma unroll
        for (int kk=0;kk<4;kk++){
          acc[r][0] += xx[kk]*wv[kk].x; acc[r][1] += xx[kk]*wv[kk].y;
          acc[r][2] += xx[kk]*wv[kk].z; acc[r][3] += xx[kk]*wv[kk].w;
        }
      }
    }
    float4 bs = *(const float4*)(bias + c0);
    #pragma unroll
    for (int r=0;r<RPG;r++){
      float o[4] = {acc[r][0]+bs.x, acc[r][1]+bs.y, acc[r][2]+bs.z, acc[r][3]+bs.w};
      #pragma unroll
      for (int q=0;q<4;q++){
        if (MODE == 0) o[q] = o[q]*sc + bb;
        if (MODE <= 1) o[q] = fmaxf(o[q], 0.f);
      }
      float4 ov = {o[0],o[1],o[2],o[3]};
      *(float4*)(Y + (r0+r)*sy + c0) = ov;
    }
  }
}

__device__ __forceinline__ void dpg_p2_group(const float* __restrict__ X, float* __restrict__ Y){
  const int t = threadIdx.x;
  if (t < 128){
    int r = t >> 4, g0 = t & 15;
    const float* p = X + r*256 + (g0&7)*8;
    float mx = p[0], smv = p[0];
    #pragma unroll
    for (int i=1;i<8;i++){ float v = p[i]; mx = fmaxf(mx, v); smv += v; }
    Y[r*256 + g0] = (g0 < 8) ? mx : smv*0.125f;
  }
}

__global__ __launch_bounds__(256, 2)
void splendor_fwd(Params P, int Bt)
{
  __shared__ float bufA[7168];
  __shared__ float bufB[7168];
  __shared__ int sflags[2];
  const int t = threadIdx.x;
  const int b0 = blockIdx.x * 8;

  if (t < 2) sflags[t] = 0;
  __syncthreads();
  {
    const unsigned int* vw = (const unsigned int*)P.valid;
    int f3 = 0, nz = 0;
    #pragma unroll
    for (int i=0;i<4;i++){
      unsigned int u = vw[t*4 + i];
      if (u & 0xFFFFFF00u) nz = 1;
      if (((u>>24)&0xFFu)==0x3Fu || ((u>>16)&0xFFu)==0x3Fu ||
          ((u>>8)&0xFFu)==0x3Fu  || (u&0xFFu)==0x3Fu) f3 = 1;
    }
    if (f3) atomicOr(&sflags[0], 1);
    if (nz) atomicOr(&sflags[1], 1);
  }
  {
    const float* inp = P.input + (size_t)b0*392;
    for (int f=t; f<3136; f+=256){
      int e = f/392, rem = f - e*392;
      int i = rem/7, j = rem - i*7;
      bufA[(e*7+j)*128 + i] = inp[f];
    }
  }
  __syncthreads();
  const int vmode = sflags[0] ? 2 : (sflags[1] ? 0 : 1);

  mm_p1<56>(bufA, bufB, P.W1, P.b1, P.g1, P.be1);   __syncthreads();
  mm_p1<128>(bufB, bufA, P.W2, P.b2, P.g2, P.be2);  __syncthreads();
  dpg_p1f(bufA, bufB, P.Wp1, P.bp1);                __syncthreads();
  mm_p1<128>(bufB, bufA, P.W3, P.b3, P.g3, P.be3);  __syncthreads();
  dpg_p1f(bufA, bufB, P.Wp2, P.bp2);                __syncthreads();
  mm_p1<128>(bufB, bufA, P.W4, P.b4, P.g4, P.be4);  __syncthreads();
  flatten_st(bufA, bufB);                           __syncthreads();

  mm_p2<704,512,4,0>(bufB,704, bufA,512, P.W5, P.b5, P.g5[0]*BN_INV, P.be5[0]); __syncthreads();
  mm_p2<512,256,2,0>(bufA,512, bufB,256, P.W6, P.b6, P.g6[0]*BN_INV, P.be6[0]); __syncthreads();
  mm_p2<192,240,2,1>(bufB+64,256, bufA+16,256, P.Wp4, P.bp4, 0.f, 0.f);
  dpg_p2_group(bufB, bufA);                         __syncthreads();
  mm_p2<256,256,2,0>(bufA,256, bufB,256, P.W7, P.b7, P.g7[0]*BN_INV, P.be7[0]); __syncthreads();
  mm_p2<256,256,2,0>(bufB,256, bufA,256, P.W8, P.b8, P.g8[0]*BN_INV, P.be8[0]); __syncthreads();
  mm_p2<192,240,2,1>(bufA+64,256, bufB+16,256, P.Wp5, P.bp5, 0.f, 0.f);
  dpg_p2_group(bufA, bufB);                         __syncthreads();
  mm_p2<256,256,2,2>(bufB,256, bufA,256,      P.Wpi1, P.bpi1, 0.f, 0.f);
  mm_p2<256,256,2,2>(bufB,256, bufA+2048,256, P.Wv1,  P.bv1,  0.f, 0.f);
  __syncthreads();

  {
    const int r = t >> 5, lq = t & 31;
    const int b = b0 + r;
    const float* hp = bufA + r*256;
    float pm[3] = {NEG_BIG, NEG_BIG, NEG_BIG};
    float mx = -INFINITY;
    #pragma unroll
    for (int p=0;p<3;p++){
      int c = lq + 32*p;
      if (c < 81){
        float s = P.bpi2[c];
        for (int k=0;k<256;k++) s += hp[k]*P.Wpi2[k*81+c];
        bool valid;
        size_t idx = (size_t)b*81 + c;
        if (vmode == 0)      valid = ((const unsigned char*)P.valid)[idx] != 0;
        else if (vmode == 1) valid = ((const int*)P.valid)[idx] != 0;
        else                 valid = ((const float*)P.valid)[idx] != 0.f;
        pm[p] = valid ? s : NEG_BIG;
        mx = fmaxf(mx, pm[p]);
      }
    }
    #pragma unroll
    for (int off=16;off;off>>=1) mx = fmaxf(mx, __shfl_xor(mx, off, 32));
    float se = 0.f;
    #pragma unroll
    for (int p=0;p<3;p++){
      int c = lq + 32*p;
      if (c < 81) se += expf(pm[p]-mx);
    }
    #pragma unroll
    for (int off=16;off;off>>=1) se += __shfl_xor(se, off, 32);
    float lse = mx + logf(se);
    #pragma unroll
    for (int p=0;p<3;p++){
      int c = lq + 32*p;
      if (c < 81) P.out[(size_t)b*81 + c] = pm[p]-lse;
    }
  }
  if (t < 8){
    const float* hv = bufA + 2048 + t*256;
    float s = P.bv2[0];
    for (int k=0;k<256;k++) s += hv[k]*P.Wv2[k];
    P.out[(size_t)Bt*81 + b0 + t] = tanhf(s);
  }
}

// ============================ launch ============================
extern "C" void kernel_launch(void* const* d_in, const int* in_sizes, int n_in,
                              void* d_out, int out_size, void* d_ws, size_t ws_size,
                              hipStream_t stream)
{
  const float* input = (const float*)d_in[0];
  const void*  valid = d_in[1];
  const float* W1  = (const float*)d_in[2];  const float* b1  = (const float*)d_in[3];
  const float* g1  = (const float*)d_in[4];  const float* be1 = (const float*)d_in[5];
  const float* W2  = (const float*)d_in[6];  const float* b2  = (const float*)d_in[7];
  const float* g2  = (const float*)d_in[8];  const float* be2 = (const float*)d_in[9];
  const float* Wp1 = (const float*)d_in[10]; const float* bp1 = (const float*)d_in[11];
  const float* W3  = (const float*)d_in[12]; const float* b3  = (const float*)d_in[13];
  const float* g3  = (const float*)d_in[14]; const float* be3 = (const float*)d_in[15];
  const float* Wp2 = (const float*)d_in[16]; const float* bp2 = (const float*)d_in[17];
  const float* W4  = (const float*)d_in[18]; const float* b4  = (const float*)d_in[19];
  const float* g4  = (const float*)d_in[20]; const float* be4 = (const float*)d_in[21];
  const float* W5  = (const float*)d_in[22]; const float* b5  = (const float*)d_in[23];
  const float* g5  = (const float*)d_in[24]; const float* be5 = (const float*)d_in[25];
  const float* W6  = (const float*)d_in[26]; const float* b6  = (const float*)d_in[27];
  const float* g6  = (const float*)d_in[28]; const float* be6 = (const float*)d_in[29];
  const float* Wp4 = (const float*)d_in[30]; const float* bp4 = (const float*)d_in[31];
  const float* W7  = (const float*)d_in[32]; const float* b7  = (const float*)d_in[33];
  const float* g7  = (const float*)d_in[34]; const float* be7 = (const float*)d_in[35];
  const float* W8  = (const float*)d_in[36]; const float* b8  = (const float*)d_in[37];
  const float* g8  = (const float*)d_in[38]; const float* be8 = (const float*)d_in[39];
  const float* Wp5 = (const float*)d_in[40]; const float* bp5 = (const float*)d_in[41];
  const float* Wpi1= (const float*)d_in[42]; const float* bpi1= (const float*)d_in[43];
  const float* Wpi2= (const float*)d_in[44]; const float* bpi2= (const float*)d_in[45];
  const float* Wv1 = (const float*)d_in[46]; const float* bv1 = (const float*)d_in[47];
  const float* Wv2 = (const float*)d_in[48]; const float* bv2 = (const float*)d_in[49];

  const long long Bt = in_sizes[0] / 392;
  const size_t need = ((size_t)OFF_X + (size_t)Bt*704) * 2;

  if (ws_size >= need && (Bt % 64) == 0) {
    ushort* wsu = (ushort*)d_ws;
    PrepParams pp;
    const float* srcs[15] = {W1,W2,W3,W4,Wp1,Wp2,W5,W6,Wp4,Wp5,W7,W8,Wpi1,Wpi2,Wv1};
    const long long offs[15] = {OFF_W1,OFF_W2,OFF_W3,OFF_W4,OFF_WP1,OFF_WP2,OFF_W5,OFF_W6,
                                OFF_WP4,OFF_WP5,OFF_W7,OFF_W8,OFF_WPI1,OFF_WPI2,OFF_WV1};
    const int Ks[15]  = {56,128,128,128, 64, 64,704,512,192,192,256,256,256,256,256};
    const int Ns[15]  = {128,128,128,128,112,112,512,256,240,240,256,256,256, 81,256};
    const int Kps[15] = {64,128,128,128, 64, 64,704,512,192,192,256,256,256,256,256};
    const int Nps[15] = {128,128,128,128,112,112,512,256,240,240,256,256,256, 96,256};
    for (int i=0;i<15;i++){
      pp.src[i]=srcs[i]; pp.off[i]=offs[i];
      pp.K[i]=Ks[i]; pp.N[i]=Ns[i]; pp.Kp[i]=Kps[i]; pp.Np[i]=Nps[i];
    }
    pp.ws = wsu;
    hipLaunchKernelGGL(prep_pack, dim3(256,15), dim3(256), 0, stream, pp);

    P1 p1;
    p1.inp = input; p1.ws = wsu; p1.xout = wsu + OFF_X;
    p1.b1=b1; p1.g1=g1; p1.be1=be1; p1.b2=b2; p1.g2=g2; p1.be2=be2; p1.bp1=bp1;
    p1.b3=b3; p1.g3=g3; p1.be3=be3; p1.bp2=bp2; p1.b4=b4; p1.g4=g4; p1.be4=be4;
    hipLaunchKernelGGL(p1_kernel, dim3((unsigned)(Bt/16)), dim3(256), 0, stream, p1);

    P2 p2;
    p2.x = wsu + OFF_X; p2.ws = wsu; p2.valid = valid;
    p2.b5=b5; p2.g5=g5; p2.be5=be5; p2.b6=b6; p2.g6=g6; p2.be6=be6; p2.bp4=bp4;
    p2.b7=b7; p2.g7=g7; p2.be7=be7; p2.b8=b8; p2.g8=g8; p2.be8=be8; p2.bp5=bp5;
    p2.bpi1=bpi1; p2.bpi2=bpi2; p2.bv1=bv1; p2.Wv2=Wv2; p2.bv2=bv2;
    p2.out = (float*)d_out; p2.Btot = Bt;
    hipLaunchKernelGGL(p2_kernel, dim3((unsigned)(Bt/64)), dim3(512), 0, stream, p2);
  } else {
    Params P;
    P.input = input; P.valid = valid;
    P.W1=W1; P.b1=b1; P.g1=g1; P.be1=be1; P.W2=W2; P.b2=b2; P.g2=g2; P.be2=be2;
    P.Wp1=Wp1; P.bp1=bp1; P.W3=W3; P.b3=b3; P.g3=g3; P.be3=be3; P.Wp2=Wp2; P.bp2=bp2;
    P.W4=W4; P.b4=b4; P.g4=g4; P.be4=be4; P.W5=W5; P.b5=b5; P.g5=g5; P.be5=be5;
    P.W6=W6; P.b6=b6; P.g6=g6; P.be6=be6; P.Wp4=Wp4; P.bp4=bp4;
    P.W7=W7; P.b7=b7; P.g7=g7; P.be7=be7; P.W8=W8; P.b8=b8; P.g8=g8; P.be8=be8;
    P.Wp5=Wp5; P.bp5=bp5; P.Wpi1=Wpi1; P.bpi1=bpi1; P.Wpi2=Wpi2; P.bpi2=bpi2;
    P.Wv1=Wv1; P.bv1=bv1; P.Wv2=Wv2; P.bv2=bv2;
    P.out = (float*)d_out;
    hipLaunchKernelGGL(splendor_fwd, dim3((unsigned)(Bt/8)), dim3(256), 0, stream, P, (int)Bt);
  }
}